// Round 7
// baseline (82.533 us; speedup 1.0000x reference)
//
#include <hip/hip_runtime.h>
#include <stdint.h>

#define IN_F 512
#define OUT_F 768
#define BD 256
#define ID 16
#define ND 256
#define CD (BD * ID)  // 4096 projection columns

typedef __bf16 bf16x8 __attribute__((ext_vector_type(8)));
typedef float f32x4 __attribute__((ext_vector_type(4)));

__device__ __forceinline__ unsigned short f2bf(float f) {
    union { float f; uint32_t u; } v; v.f = f;
    uint32_t u = v.u + 0x7FFFu + ((v.u >> 16) & 1u);  // RNE
    return (unsigned short)(u >> 16);
}

// ---- prep: T->Tt blocked bf16 [f>>3][c][f&7]; x->xbf; out init + concat ----
// blocks [0,2048): T convert. [2048,2112): x convert.
// [2112,2176): out[:,512:768] = -1.  [2176,2304): out[b,0:512] = x[b,:].
__global__ __launch_bounds__(256) void prep_kernel(const float* __restrict__ x,
                                                   const float* __restrict__ T,
                                                   unsigned short* __restrict__ Tt,
                                                   unsigned short* __restrict__ xbf,
                                                   float* __restrict__ out) {
    const int bid = blockIdx.x;
    const int t = threadIdx.x;
    if (bid < 2048) {
        int gidx = bid * 256 + t;
        int f = gidx >> 10;              // 0..511
        int c = (gidx & 1023) * 4;       // 0..4092
        float4 v = *reinterpret_cast<const float4*>(T + (size_t)f * CD + c);
        unsigned short* base = Tt + (size_t)(f >> 3) * (CD * 8) + (f & 7);
        base[(size_t)(c + 0) * 8] = f2bf(v.x);
        base[(size_t)(c + 1) * 8] = f2bf(v.y);
        base[(size_t)(c + 2) * 8] = f2bf(v.z);
        base[(size_t)(c + 3) * 8] = f2bf(v.w);
    } else if (bid < 2112) {
        int i0 = ((bid - 2048) * 256 + t) * 8;
        float4 a = *reinterpret_cast<const float4*>(x + i0);
        float4 b = *reinterpret_cast<const float4*>(x + i0 + 4);
        union { unsigned short s[8]; uint4 v; } u;
        u.s[0] = f2bf(a.x); u.s[1] = f2bf(a.y); u.s[2] = f2bf(a.z); u.s[3] = f2bf(a.w);
        u.s[4] = f2bf(b.x); u.s[5] = f2bf(b.y); u.s[6] = f2bf(b.z); u.s[7] = f2bf(b.w);
        *reinterpret_cast<uint4*>(xbf + i0) = u.v;
    } else if (bid < 2176) {
        int gid = (bid - 2112) * 256 + t;   // 0..16383, one float4 each
        int n = gid >> 6, q = gid & 63;     // 64 float4 per disc row
        *reinterpret_cast<float4*>(out + (size_t)n * OUT_F + IN_F + q * 4) =
            make_float4(-1.f, -1.f, -1.f, -1.f);
    } else {
        int gid = (bid - 2176) * 256 + t;   // 0..32767
        int r = gid >> 7, q = gid & 127;    // 128 float4 per x row
        float4 v = reinterpret_cast<const float4*>(x + (size_t)r * IN_F)[q];
        reinterpret_cast<float4*>(out + (size_t)r * OUT_F)[q] = v;
    }
}

// ---- gemm: block (b, nh): M[b][nh*128..+128][0:16] via mfma 16x16x32 bf16 ----
// grid 512 x 256thr. Wave w: 2 n-tiles, B-fragment shared across both MFMAs.
__global__ __launch_bounds__(256) void gemm_kernel(const unsigned short* __restrict__ xbf,
                                                   const unsigned short* __restrict__ Tt,
                                                   float* __restrict__ M) {
    const int t = threadIdx.x;
    const int lane = t & 63;
    const int w = t >> 6;
    const int b = blockIdx.x >> 1;
    const int nh = blockIdx.x & 1;
    const int rc = lane & 15;   // A row within tile == B col (=i) == D col
    const int g = lane >> 4;    // k-group 0..3

    const bf16x8* Av = reinterpret_cast<const bf16x8*>(xbf);
    const bf16x8* Bv = reinterpret_cast<const bf16x8*>(Tt);
    const int nt0 = nh * 8 + w * 2;
    const int nt1 = nt0 + 1;
    const int c = b * 16 + rc;

    f32x4 acc0 = {0.f, 0.f, 0.f, 0.f};
    f32x4 acc1 = {0.f, 0.f, 0.f, 0.f};
    const int ab0 = (nt0 * 16 + rc) * (IN_F / 8) + g;
    const int ab1 = (nt1 * 16 + rc) * (IN_F / 8) + g;
    const int bb = g * CD + c;
#pragma unroll 4
    for (int kk = 0; kk < 16; ++kk) {
        bf16x8 bv = Bv[bb + kk * 4 * CD];
        acc0 = __builtin_amdgcn_mfma_f32_16x16x32_bf16(Av[ab0 + kk * 4], bv, acc0, 0, 0, 0);
        acc1 = __builtin_amdgcn_mfma_f32_16x16x32_bf16(Av[ab1 + kk * 4], bv, acc1, 0, 0, 0);
    }
    // D layout (m89): col = lane&15, row = g*4 + r
    float* Mo = M + (size_t)b * (ND * ID) + rc;
#pragma unroll
    for (int r = 0; r < 4; ++r) {
        Mo[(size_t)(nt0 * 16 + g * 4 + r) * ID] = acc0[r];
        Mo[(size_t)(nt1 * 16 + g * 4 + r) * ID] = acc1[r];
    }
}

// ---- pair: grid 2048 = (b, js of 8); 32 j each; atomicAdd into out ----
// js blockIdx-derived => provably uniform => mj stays s_load broadcast.
__global__ __launch_bounds__(256) void pair_kernel(const float* __restrict__ M,
                                                   float* __restrict__ out) {
    const int js = blockIdx.x & 7;
    const int b = blockIdx.x >> 3;
    const int n = threadIdx.x;
    const float* Mb = M + (size_t)b * (ND * ID);

    float m[ID];
#pragma unroll
    for (int i = 0; i < ID; i += 4) {
        float4 v = *reinterpret_cast<const float4*>(Mb + (size_t)n * ID + i);
        m[i] = v.x; m[i + 1] = v.y; m[i + 2] = v.z; m[i + 3] = v.w;
    }
    float tot = 0.f;
    const int j0 = js * (ND / 8);
#pragma unroll 2
    for (int j = j0; j < j0 + ND / 8; ++j) {
        const float* mj = Mb + (size_t)j * ID;  // uniform -> s_load_dwordx16
        float s0 = 0.f, s1 = 0.f, s2 = 0.f, s3 = 0.f;
#pragma unroll
        for (int i = 0; i < ID; i += 4) {
            s0 += fabsf(m[i + 0] - mj[i + 0]);
            s1 += fabsf(m[i + 1] - mj[i + 1]);
            s2 += fabsf(m[i + 2] - mj[i + 2]);
            s3 += fabsf(m[i + 3] - mj[i + 3]);
        }
        tot += __expf(-((s0 + s1) + (s2 + s3)));
    }
    atomicAdd(out + (size_t)n * OUT_F + IN_F + b, tot);
}

// ---- fallback (ws too small): R1 fused kernel (known-good ~74us) ----
__global__ __launch_bounds__(256) void mbd_fallback(const float* __restrict__ x,
                                                    const float* __restrict__ T,
                                                    float* __restrict__ out) {
    __shared__ float Ml[ND * ID];
    const int b = blockIdx.x;
    const int n = threadIdx.x;
    float m[ID];
#pragma unroll
    for (int i = 0; i < ID; ++i) m[i] = 0.f;
    const float4* xr = reinterpret_cast<const float4*>(x + (size_t)n * IN_F);
    const float* Tb = T + (size_t)b * ID;
    for (int f4 = 0; f4 < IN_F / 4; ++f4) {
        float4 xv = xr[f4];
        const float* t0 = Tb + (size_t)(4 * f4) * CD;
#pragma unroll
        for (int i = 0; i < ID; ++i) m[i] = fmaf(xv.x, t0[i], m[i]);
#pragma unroll
        for (int i = 0; i < ID; ++i) m[i] = fmaf(xv.y, t0[CD + i], m[i]);
#pragma unroll
        for (int i = 0; i < ID; ++i) m[i] = fmaf(xv.z, t0[2 * CD + i], m[i]);
#pragma unroll
        for (int i = 0; i < ID; ++i) m[i] = fmaf(xv.w, t0[3 * CD + i], m[i]);
    }
#pragma unroll
    for (int i = 0; i < ID; i += 4)
        *reinterpret_cast<float4*>(&Ml[n * ID + i]) =
            make_float4(m[i], m[i + 1], m[i + 2], m[i + 3]);
    __syncthreads();
    float tot = 0.f;
    for (int j = 0; j < ND; ++j) {
        const float* mj = &Ml[j * ID];
        float s0 = 0.f, s1 = 0.f, s2 = 0.f, s3 = 0.f;
#pragma unroll
        for (int i = 0; i < ID; i += 4) {
            s0 += fabsf(m[i + 0] - mj[i + 0]);
            s1 += fabsf(m[i + 1] - mj[i + 1]);
            s2 += fabsf(m[i + 2] - mj[i + 2]);
            s3 += fabsf(m[i + 3] - mj[i + 3]);
        }
        tot += __expf(-((s0 + s1) + (s2 + s3)));
    }
    out[(size_t)n * OUT_F + IN_F + b] = tot - 1.f;
    if (n < IN_F / 4) {
        const float4* xs = reinterpret_cast<const float4*>(x + (size_t)b * IN_F);
        reinterpret_cast<float4*>(out + (size_t)b * OUT_F)[n] = xs[n];
    }
}

extern "C" void kernel_launch(void* const* d_in, const int* in_sizes, int n_in,
                              void* d_out, int out_size, void* d_ws, size_t ws_size,
                              hipStream_t stream) {
    const float* x = (const float*)d_in[0];
    const float* T = (const float*)d_in[1];
    float* out = (float*)d_out;

    // ws layout: Tt bf16 @0 (4 MB) | xbf bf16 @4 MB (256 KB) | M f32 @4.25 MB (4 MB)
    const size_t off_xbf = 4194304;
    const size_t off_M = off_xbf + 262144;
    const size_t needed = off_M + 4194304;  // 8,650,752 B

    if (ws_size >= needed) {
        unsigned short* Tt = (unsigned short*)d_ws;
        unsigned short* xbf = (unsigned short*)((char*)d_ws + off_xbf);
        float* M = (float*)((char*)d_ws + off_M);
        prep_kernel<<<dim3(2304), dim3(256), 0, stream>>>(x, T, Tt, xbf, out);
        gemm_kernel<<<dim3(512), dim3(256), 0, stream>>>(xbf, Tt, M);
        pair_kernel<<<dim3(2048), dim3(256), 0, stream>>>(M, out);
    } else {
        mbd_fallback<<<dim3(BD), dim3(256), 0, stream>>>(x, T, out);
    }
}

// Round 8
// 46.373 us; speedup vs baseline: 1.7798x; 1.7798x over previous
//
#include <hip/hip_runtime.h>
#include <stdint.h>

#define IN_F 512
#define OUT_F 768
#define ID 16
#define ND 256
#define CD 4096   // T row stride in floats (B*I)
#define MS 20     // LDS slab row stride in floats (16 + 4 pad -> b128 mj, 2-way writes)

typedef __bf16 bf16x8 __attribute__((ext_vector_type(8)));
typedef float f32x4 __attribute__((ext_vector_type(4)));

// One block per feature b. 256 threads = 4 waves.
// Phase G: M[b] slab (256x16) via mfma 16x16x32 bf16, T staged f32 in LDS.
// Phase P: thread (w,l) holds rows {l,l+64,l+128,l+192} in VGPRs; wave w
//          handles j in [w*64,(w+1)*64); mj = 4 uniform ds_read_b128.
__global__ __launch_bounds__(256) void mbd_one(const float* __restrict__ x,
                                               const float* __restrict__ T,
                                               float* __restrict__ out) {
    __shared__ float Tsh[IN_F * ID];  // 32 KB, [f][c] f32; reused as `red` at end
    __shared__ float Msh[ND * MS];    // 20 KB padded slab
    const int b = blockIdx.x;
    const int t = threadIdx.x;
    const int lane = t & 63;
    const int w = t >> 6;

    // ---- stage T[:, b, :] (512 x 16 f32 = 32 KB) ----
#pragma unroll
    for (int s = 0; s < 8; ++s) {
        int q = s * 256 + t;
        int f = q >> 2, c4 = (q & 3) << 2;
        float4 v = *reinterpret_cast<const float4*>(T + (size_t)f * CD + b * ID + c4);
        *reinterpret_cast<float4*>(&Tsh[f * ID + c4]) = v;
    }
    __syncthreads();

    // ---- phase G: wave w computes n-tiles {4w..4w+3} ----
    const int rc = lane & 15;  // A row within tile == B col (i) == D col
    const int g = lane >> 4;   // k-group
    f32x4 acc[4];
#pragma unroll
    for (int i = 0; i < 4; ++i) acc[i] = f32x4{0.f, 0.f, 0.f, 0.f};

    const float* xw = x + (size_t)(w * 64 + rc) * IN_F;
    for (int k = 0; k < 16; ++k) {
        bf16x8 bfr;
#pragma unroll
        for (int e = 0; e < 8; ++e)
            bfr[e] = (__bf16)Tsh[(k * 32 + g * 8 + e) * ID + rc];
        const int xo = k * 32 + g * 8;
#pragma unroll
        for (int nt = 0; nt < 4; ++nt) {
            const float* ap = xw + (size_t)nt * 16 * IN_F + xo;
            float4 a0 = *reinterpret_cast<const float4*>(ap);
            float4 a1 = *reinterpret_cast<const float4*>(ap + 4);
            bf16x8 afr;
            afr[0] = (__bf16)a0.x; afr[1] = (__bf16)a0.y;
            afr[2] = (__bf16)a0.z; afr[3] = (__bf16)a0.w;
            afr[4] = (__bf16)a1.x; afr[5] = (__bf16)a1.y;
            afr[6] = (__bf16)a1.z; afr[7] = (__bf16)a1.w;
            acc[nt] = __builtin_amdgcn_mfma_f32_16x16x32_bf16(afr, bfr, acc[nt], 0, 0, 0);
        }
    }

    // slab write: D layout (m89): col = lane&15, row = g*4 + r (2-way banks, free)
#pragma unroll
    for (int nt = 0; nt < 4; ++nt)
#pragma unroll
        for (int r = 0; r < 4; ++r)
            Msh[((w * 4 + nt) * 16 + g * 4 + r) * MS + rc] = acc[nt][r];
    __syncthreads();

    // ---- phase P: own rows {lane + 64r} -> 8-way one-time reads ----
    float mr[4][ID];
#pragma unroll
    for (int r = 0; r < 4; ++r)
#pragma unroll
        for (int ii = 0; ii < 4; ++ii) {
            float4 v = *reinterpret_cast<const float4*>(
                &Msh[(lane + 64 * r) * MS + ii * 4]);
            mr[r][ii * 4] = v.x; mr[r][ii * 4 + 1] = v.y;
            mr[r][ii * 4 + 2] = v.z; mr[r][ii * 4 + 3] = v.w;
        }

    float pacc[4] = {0.f, 0.f, 0.f, 0.f};
    const int j0 = w * 64;
#pragma unroll 2
    for (int j = j0; j < j0 + 64; ++j) {
        float mj[ID];
#pragma unroll
        for (int ii = 0; ii < 4; ++ii) {  // uniform addr -> broadcast b128
            float4 v = *reinterpret_cast<const float4*>(&Msh[j * MS + ii * 4]);
            mj[ii * 4] = v.x; mj[ii * 4 + 1] = v.y;
            mj[ii * 4 + 2] = v.z; mj[ii * 4 + 3] = v.w;
        }
#pragma unroll
        for (int r = 0; r < 4; ++r) {
            float s0 = 0.f, s1 = 0.f, s2 = 0.f, s3 = 0.f;
#pragma unroll
            for (int i = 0; i < ID; i += 4) {
                s0 += fabsf(mr[r][i + 0] - mj[i + 0]);
                s1 += fabsf(mr[r][i + 1] - mj[i + 1]);
                s2 += fabsf(mr[r][i + 2] - mj[i + 2]);
                s3 += fabsf(mr[r][i + 3] - mj[i + 3]);
            }
            pacc[r] += __expf(-((s0 + s1) + (s2 + s3)));
        }
    }

    // ---- cross-wave reduce (reuse Tsh) ----
    float* red = Tsh;  // rows covered: red[w*256 + row]
#pragma unroll
    for (int r = 0; r < 4; ++r) red[w * 256 + lane + 64 * r] = pacc[r];
    __syncthreads();
    {
        float s = red[t] + red[256 + t] + red[512 + t] + red[768 + t] - 1.0f;
        out[(size_t)t * OUT_F + IN_F + b] = s;  // self-pair exp(0)=1 cancels -1
    }
    // concat: out[b, 0:512] = x[b, :]
    if (t < IN_F / 4) {
        float4 v = reinterpret_cast<const float4*>(x + (size_t)b * IN_F)[t];
        reinterpret_cast<float4*>(out + (size_t)b * OUT_F)[t] = v;
    }
}

extern "C" void kernel_launch(void* const* d_in, const int* in_sizes, int n_in,
                              void* d_out, int out_size, void* d_ws, size_t ws_size,
                              hipStream_t stream) {
    const float* x = (const float*)d_in[0];
    const float* T = (const float*)d_in[1];
    float* out = (float*)d_out;
    mbd_one<<<dim3(256), dim3(256), 0, stream>>>(x, T, out);
}